// Round 9
// baseline (625.611 us; speedup 1.0000x reference)
//
#include <hip/hip_runtime.h>
#include <stdint.h>

#define NODES 16384
#define D0    263
#define K1PAD 288
#define OUTW  1031   // 263 + 256*3
#define NGRP  128    // channel groups of 2

typedef __attribute__((ext_vector_type(8))) short bf16x8;
typedef __attribute__((ext_vector_type(4))) float f32x4;
typedef __attribute__((ext_vector_type(2))) unsigned short u16x2;

__device__ __forceinline__ float bf2f(unsigned short u) {
    union { unsigned int i; float f; } c; c.i = ((unsigned int)u) << 16; return c.f;
}
__device__ __forceinline__ unsigned short f2bf(float f) {
    union { float f; unsigned int i; } c; c.f = f;
    unsigned int x = c.i;
    unsigned int r = (x + 0x7fffu + ((x >> 16) & 1u)) >> 16;
    return (unsigned short)r;
}
// order-preserving bf16 -> u16 key (unsigned max == float max)
__device__ __forceinline__ unsigned short bf2key(unsigned short b) {
    return (b & 0x8000u) ? (unsigned short)~b : (unsigned short)(b | 0x8000u);
}
__device__ __forceinline__ unsigned short key2bf(unsigned short k) {
    return (k & 0x8000u) ? (unsigned short)(k ^ 0x8000u) : (unsigned short)~k;
}
__device__ __forceinline__ u16x2 as_u16x2(unsigned int x) {
    union { unsigned int u; u16x2 v; } c; c.u = x; return c.v;
}

// ------------------------------------------------- detect dtypes + zero deg
// flags[0]: edge_index is int64 ; flags[1]: floats are f32
__global__ void detect_zero_kernel(const void* __restrict__ ei, const void* __restrict__ pooled,
                                   int* __restrict__ flags, int* __restrict__ deg) {
    int idx = blockIdx.x * 256 + threadIdx.x;
    deg[idx] = 0;
    if (blockIdx.x == 0 && threadIdx.x < 64) {
        int lane = threadIdx.x;
        const long long* e64 = (const long long*)ei;
        bool ok = true;
        for (int i = lane; i < 512; i += 64) {
            long long v = e64[i];
            if (v < 0 || v >= NODES) ok = false;
        }
        unsigned long long b = __ballot(ok);
        const unsigned short* ph = (const unsigned short*)pooled;
        int hits = 0;
        for (int i = lane; i < 512; i += 64) {
            int e = (ph[i] >> 7) & 0xFF;
            if (e >= 0x90) hits++;   // |v| >= 2^17: impossible for N(0,1) bf16 data
        }
        for (int off = 32; off; off >>= 1) hits += __shfl_down(hits, off);
        if (lane == 0) {
            flags[0] = (b == ~0ull) ? 1 : 0;
            flags[1] = (hits > 8) ? 1 : 0;
        }
    }
}

// ---------------------------------------------------------------- edge sort
__global__ void hist_kernel(const void* __restrict__ ei, int E, const int* __restrict__ flags,
                            int* __restrict__ deg) {
    int e = blockIdx.x * blockDim.x + threadIdx.x;
    if (e >= E) return;
    int d = flags[0] ? (int)((const long long*)ei)[(size_t)E + e]
                     : ((const int*)ei)[(size_t)E + e];
    atomicAdd(&deg[d], 1);
}

__global__ void scan_kernel(const int* __restrict__ deg, int* __restrict__ offs,
                            int* __restrict__ cursor) {
    __shared__ int part[256];
    int tid = threadIdx.x;
    int base = tid * 64;
    int s = 0;
    for (int i = 0; i < 64; ++i) s += deg[base + i];
    part[tid] = s;
    __syncthreads();
    for (int off = 1; off < 256; off <<= 1) {
        int t = (tid >= off) ? part[tid - off] : 0;
        __syncthreads();
        part[tid] += t;
        __syncthreads();
    }
    int run = (tid > 0) ? part[tid - 1] : 0;
    for (int i = 0; i < 64; ++i) {
        int idx = base + i;
        offs[idx] = run;
        cursor[idx] = run;
        run += deg[idx];
    }
    if (tid == 255) offs[NODES] = run;
}

__global__ void scatter_kernel(const void* __restrict__ ei, int E, const int* __restrict__ flags,
                               int* __restrict__ cursor, int* __restrict__ ssrc) {
    int e = blockIdx.x * blockDim.x + threadIdx.x;
    if (e >= E) return;
    int s, d;
    if (flags[0]) {
        const long long* p = (const long long*)ei;
        s = (int)p[e];
        d = (int)p[(size_t)E + e];
    } else {
        const int* p = (const int*)ei;
        s = p[e];
        d = p[(size_t)E + e];
    }
    int pos = atomicAdd(&cursor[d], 1);
    ssrc[pos] = s;
}

// ------------------------------------------- x0 staging + weight prep fused
#define T0 (NODES * K1PAD)
#define S1 (512 * K1PAD)
#define S2 (512 * 256)
__global__ void setup_kernel(const void* __restrict__ pooled, const void* __restrict__ rois,
                             const void* __restrict__ W1, const void* __restrict__ W2,
                             const void* __restrict__ W3, const int* __restrict__ flags,
                             unsigned short* __restrict__ x0p, void* __restrict__ outv,
                             unsigned short* __restrict__ wc1, unsigned short* __restrict__ wc2,
                             unsigned short* __restrict__ wc3) {
    int idx = blockIdx.x * 256 + threadIdx.x;
    bool f32m = flags[1] != 0;
    if (idx < T0) {
        int node = idx / K1PAD;
        int k = idx - node * K1PAD;
        float val = 0.f;
        if (k < 256) {
            val = f32m ? ((const float*)pooled)[(size_t)node * 256 + k]
                       : bf2f(((const unsigned short*)pooled)[(size_t)node * 256 + k]);
        } else if (k < D0) {
            val = f32m ? ((const float*)rois)[(size_t)node * 7 + (k - 256)]
                       : bf2f(((const unsigned short*)rois)[(size_t)node * 7 + (k - 256)]);
        }
        x0p[idx] = f2bf(val);
        if (k < D0) {
            if (f32m) ((float*)outv)[(size_t)node * OUTW + k] = val;
            else      ((unsigned short*)outv)[(size_t)node * OUTW + k] = f2bf(val);
        }
        return;
    }
    idx -= T0;
    if (idx < S1) {
        // layer 1: W1 is [256][526], in=263 padded to 288
        int r = idx / K1PAD;
        int k = idx - r * K1PAD;
        unsigned short val = 0;
        if (k < D0) {
            if (r < 256) {
                float a = f32m ? ((const float*)W1)[(size_t)r * 526 + k]
                               : bf2f(((const unsigned short*)W1)[(size_t)r * 526 + k]);
                val = f2bf(a);
            } else {
                size_t ro = (size_t)(r - 256) * 526;
                float a, b;
                if (f32m) { a = ((const float*)W1)[ro + k]; b = ((const float*)W1)[ro + D0 + k]; }
                else      { a = bf2f(((const unsigned short*)W1)[ro + k]);
                            b = bf2f(((const unsigned short*)W1)[ro + D0 + k]); }
                val = f2bf(b - a);
            }
        }
        wc1[idx] = val;
        return;
    }
    idx -= S1;
    const void* W = (idx < S2) ? W2 : W3;
    unsigned short* wc = (idx < S2) ? wc2 : wc3;
    if (idx >= S2) idx -= S2;
    int r = idx >> 8;
    int k = idx & 255;
    unsigned short val;
    if (r < 256) {
        float a = f32m ? ((const float*)W)[(size_t)r * 512 + k]
                       : bf2f(((const unsigned short*)W)[(size_t)r * 512 + k]);
        val = f2bf(a);
    } else {
        size_t ro = (size_t)(r - 256) * 512;
        float a, b;
        if (f32m) { a = ((const float*)W)[ro + k]; b = ((const float*)W)[ro + 256 + k]; }
        else      { a = bf2f(((const unsigned short*)W)[ro + k]);
                    b = bf2f(((const unsigned short*)W)[ro + 256 + k]); }
        val = f2bf(b - a);
    }
    wc[idx] = val;
}

// ---------------------------------------------------------------- GEMM
// T[M,512] = A[M,K]*Wc[512,K]^T.
// cols 0..255  -> u keys in grouped layout u_g[g=c>>1][node][c&1]   (u16 key)
// cols 256..511-> vb_g[g][node][c&1] = v + bias (f32)
// wave = 64x64 (acc[4][4]); block 64x256; grid (M/64, 2).
template <int K>
__global__ __launch_bounds__(256) void gemm_kernel(const unsigned short* __restrict__ A,
                                                   const unsigned short* __restrict__ Wc,
                                                   const void* __restrict__ bias,
                                                   const int* __restrict__ flags,
                                                   unsigned short* __restrict__ u_g,
                                                   float* __restrict__ vb_g) {
    int lane = threadIdx.x & 63;
    int wave = threadIdx.x >> 6;
    int row0 = blockIdx.x * 64;
    int col0 = blockIdx.y * 256 + wave * 64;
    int lr = lane & 15;
    int kb = (lane >> 4) * 8;
    const unsigned short* Ap = A + (size_t)(row0 + lr) * K + kb;
    const unsigned short* Wp = Wc + (size_t)(col0 + lr) * K + kb;

    f32x4 acc[4][4];
    #pragma unroll
    for (int i = 0; i < 4; ++i)
        #pragma unroll
        for (int j = 0; j < 4; ++j) acc[i][j] = (f32x4){0.f, 0.f, 0.f, 0.f};

    for (int k0 = 0; k0 < K; k0 += 32) {
        bf16x8 a[4], b[4];
        #pragma unroll
        for (int i = 0; i < 4; ++i) a[i] = *reinterpret_cast<const bf16x8*>(Ap + (size_t)i * 16 * K + k0);
        #pragma unroll
        for (int i = 0; i < 4; ++i) b[i] = *reinterpret_cast<const bf16x8*>(Wp + (size_t)i * 16 * K + k0);
        #pragma unroll
        for (int rb = 0; rb < 4; ++rb)
            #pragma unroll
            for (int cb = 0; cb < 4; ++cb)
                acc[rb][cb] = __builtin_amdgcn_mfma_f32_16x16x32_bf16(a[rb], b[cb], acc[rb][cb], 0, 0, 0);
    }

    bool is_u = (blockIdx.y == 0);
    bool f32m = flags[1] != 0;
    #pragma unroll
    for (int rb = 0; rb < 4; ++rb) {
        int rbase = row0 + rb * 16 + (lane >> 4) * 4;
        #pragma unroll
        for (int cb = 0; cb < 4; ++cb) {
            int c = col0 + cb * 16 + lr;
            if (is_u) {
                int g = c >> 1;
                size_t base = (size_t)g * 32768 + (c & 1);
                #pragma unroll
                for (int reg = 0; reg < 4; ++reg) {
                    int r = rbase + reg;
                    u_g[base + (size_t)r * 2] = bf2key(f2bf(acc[rb][cb][reg]));
                }
            } else {
                int c2 = c - 256;
                int g = c2 >> 1;
                float bv = f32m ? ((const float*)bias)[c2]
                                : bf2f(((const unsigned short*)bias)[c2]);
                size_t base = (size_t)g * 32768 + (c2 & 1);
                #pragma unroll
                for (int reg = 0; reg < 4; ++reg) {
                    int r = rbase + reg;
                    vb_g[base + (size_t)r * 2] = acc[rb][cb][reg] + bv;
                }
            }
        }
    }
}

// ---------------------------------------------------------------- combine
// grid = 2 chunks x 128 groups (chunk-major: consecutive blocks share the
// same ssrc slice in L2). Block stages its group's 64 KB [16384 nodes x 2ch]
// key slice into LDS, then thread-per-node walks the edge list gathering
// 4 B/edge from LDS. Writes packed bf16 pair to xcur_t[g][node] (coalesced).
__global__ __launch_bounds__(256) void combine_kernel(const unsigned short* __restrict__ u_g,
                                                      const float* __restrict__ vb_g,
                                                      const int* __restrict__ offs,
                                                      const int* __restrict__ ssrc,
                                                      unsigned int* __restrict__ xcur_t) {
    __shared__ unsigned int uslice[NODES];   // 64 KB: [node] -> 2 packed keys
    int g = blockIdx.x & (NGRP - 1);
    int chunk = blockIdx.x >> 7;
    int tid = threadIdx.x;

    const uint4* s4 = (const uint4*)(u_g + (size_t)g * 32768);
    uint4* d4 = (uint4*)uslice;
    #pragma unroll
    for (int i = 0; i < 16; ++i) d4[tid + i * 256] = s4[tid + i * 256];
    __syncthreads();

    const float2* vb2 = (const float2*)(vb_g + (size_t)g * 32768);
    unsigned int* xt = xcur_t + (size_t)g * NODES;
    int nbase = chunk * 8192 + tid;

    for (int k = 0; k < 32; ++k) {
        int n = nbase + k * 256;
        int s0 = offs[n], s1 = offs[n + 1];
        u16x2 mk = (u16x2)0;
        int e = s0;
        for (; e + 3 < s1; e += 4) {
            int i0 = ssrc[e], i1 = ssrc[e + 1], i2 = ssrc[e + 2], i3 = ssrc[e + 3];
            u16x2 k0 = as_u16x2(uslice[i0]);
            u16x2 k1 = as_u16x2(uslice[i1]);
            u16x2 k2 = as_u16x2(uslice[i2]);
            u16x2 k3 = as_u16x2(uslice[i3]);
            mk = __builtin_elementwise_max(mk, __builtin_elementwise_max(
                     __builtin_elementwise_max(k0, k1), __builtin_elementwise_max(k2, k3)));
        }
        for (; e < s1; ++e)
            mk = __builtin_elementwise_max(mk, as_u16x2(uslice[ssrc[e]]));

        float m0 = bf2f(key2bf(mk[0]));
        float m1 = bf2f(key2bf(mk[1]));
        float2 vv = vb2[n];
        bool nz = (s1 > s0);
        float r0 = nz ? fmaxf(m0 + vv.x, 0.f) : 0.f;
        float r1 = nz ? fmaxf(m1 + vv.y, 0.f) : 0.f;
        xt[n] = (unsigned int)f2bf(r0) | ((unsigned int)f2bf(r1) << 16);
    }
}

// ---------------------------------------------------------------- fixup
// transpose xcur_t[g][node] -> x_cur[node][256] bf16 + out slice (dtype per flag)
__global__ __launch_bounds__(256) void fixup_kernel(const unsigned int* __restrict__ xcur_t,
                                                    const int* __restrict__ flags,
                                                    unsigned short* __restrict__ x_cur,
                                                    void* __restrict__ outv,
                                                    int col_off) {
    __shared__ unsigned int tile[32][NGRP + 1];
    int n0 = blockIdx.x * 32;
    int t = threadIdx.x;
    #pragma unroll
    for (int it = 0; it < 16; ++it) {
        int flat = it * 256 + t;
        int g = flat >> 5, j = flat & 31;
        tile[j][g] = xcur_t[(size_t)g * NODES + n0 + j];
    }
    __syncthreads();
    bool f32m = flags[1] != 0;
    int n = t >> 3, seg = t & 7;
    int node = n0 + n;
    unsigned int* xc = (unsigned int*)(x_cur + (size_t)node * 256) + seg * 16;
    size_t ob = (size_t)node * OUTW + col_off + seg * 32;
    #pragma unroll
    for (int k2 = 0; k2 < 16; ++k2) {
        unsigned int w = tile[n][seg * 16 + k2];
        xc[k2] = w;
        unsigned short h0 = (unsigned short)(w & 0xffff);
        unsigned short h1 = (unsigned short)(w >> 16);
        if (f32m) {
            ((float*)outv)[ob + k2 * 2]     = bf2f(h0);
            ((float*)outv)[ob + k2 * 2 + 1] = bf2f(h1);
        } else {
            ((unsigned short*)outv)[ob + k2 * 2]     = h0;
            ((unsigned short*)outv)[ob + k2 * 2 + 1] = h1;
        }
    }
}

// ---------------------------------------------------------------- launch
extern "C" void kernel_launch(void* const* d_in, const int* in_sizes, int n_in,
                              void* d_out, int out_size, void* d_ws, size_t ws_size,
                              hipStream_t stream) {
    const void* rois   = d_in[0];
    const void* pooled = d_in[1];
    const void* ei     = d_in[2];
    const void* W1 = d_in[3];
    const void* b1 = d_in[4];
    const void* W2 = d_in[5];
    const void* b2 = d_in[6];
    const void* W3 = d_in[7];
    const void* b3 = d_in[8];

    const int E = in_sizes[2] / 2;

    char* ws = (char*)d_ws;
    size_t o = 0;
    auto take = [&](size_t bytes) { size_t cur = o; o += (bytes + 255) & ~(size_t)255; return cur; };
    int* flags           = (int*)(ws + take(8));
    int* deg             = (int*)(ws + take(sizeof(int) * NODES));
    int* offs            = (int*)(ws + take(sizeof(int) * (NODES + 1)));
    int* cursor          = (int*)(ws + take(sizeof(int) * NODES));
    int* ssrc            = (int*)(ws + take(sizeof(int) * (size_t)E));
    unsigned short* x0p  = (unsigned short*)(ws + take(2ull * NODES * K1PAD));
    unsigned short* wc1  = (unsigned short*)(ws + take(2ull * 512 * K1PAD));
    unsigned short* wc2  = (unsigned short*)(ws + take(2ull * 512 * 256));
    unsigned short* wc3  = (unsigned short*)(ws + take(2ull * 512 * 256));
    unsigned short* u_g  = (unsigned short*)(ws + take(2ull * NODES * 256));
    float*          vb_g = (float*)(ws + take(4ull * NODES * 256));
    unsigned int*  xcurt = (unsigned int*)(ws + take(4ull * NODES * NGRP / 1 / 2 * 2)); // 8 MB
    unsigned short* xcur = (unsigned short*)(ws + take(2ull * NODES * 256));
    (void)ws_size;

    const int eb = (E + 255) / 256;

    detect_zero_kernel<<<NODES / 256, 256, 0, stream>>>(ei, pooled, flags, deg);
    hist_kernel<<<eb, 256, 0, stream>>>(ei, E, flags, deg);
    scan_kernel<<<1, 256, 0, stream>>>(deg, offs, cursor);
    scatter_kernel<<<eb, 256, 0, stream>>>(ei, E, flags, cursor, ssrc);

    setup_kernel<<<(T0 + S1 + 2 * S2) / 256, 256, 0, stream>>>(pooled, rois, W1, W2, W3, flags,
                                                               x0p, d_out, wc1, wc2, wc3);

    // layer 1
    gemm_kernel<K1PAD><<<dim3(NODES / 64, 2), 256, 0, stream>>>(x0p, wc1, b1, flags, u_g, vb_g);
    combine_kernel<<<2 * NGRP, 256, 0, stream>>>(u_g, vb_g, offs, ssrc, xcurt);
    fixup_kernel<<<NODES / 32, 256, 0, stream>>>(xcurt, flags, xcur, d_out, D0);

    // layer 2
    gemm_kernel<256><<<dim3(NODES / 64, 2), 256, 0, stream>>>(xcur, wc2, b2, flags, u_g, vb_g);
    combine_kernel<<<2 * NGRP, 256, 0, stream>>>(u_g, vb_g, offs, ssrc, xcurt);
    fixup_kernel<<<NODES / 32, 256, 0, stream>>>(xcurt, flags, xcur, d_out, D0 + 256);

    // layer 3
    gemm_kernel<256><<<dim3(NODES / 64, 2), 256, 0, stream>>>(xcur, wc3, b3, flags, u_g, vb_g);
    combine_kernel<<<2 * NGRP, 256, 0, stream>>>(u_g, vb_g, offs, ssrc, xcurt);
    fixup_kernel<<<NODES / 32, 256, 0, stream>>>(xcurt, flags, xcur, d_out, D0 + 512);
}

// Round 10
// 535.682 us; speedup vs baseline: 1.1679x; 1.1679x over previous
//
#include <hip/hip_runtime.h>
#include <stdint.h>

#define NODES 16384
#define D0    263
#define K1PAD 288
#define OUTW  1031   // 263 + 256*3
#define NGRP  128    // channel groups of 2

typedef __attribute__((ext_vector_type(8))) short bf16x8;
typedef __attribute__((ext_vector_type(4))) float f32x4;
typedef __attribute__((ext_vector_type(2))) unsigned short u16x2;

__device__ __forceinline__ float bf2f(unsigned short u) {
    union { unsigned int i; float f; } c; c.i = ((unsigned int)u) << 16; return c.f;
}
__device__ __forceinline__ unsigned short f2bf(float f) {
    union { float f; unsigned int i; } c; c.f = f;
    unsigned int x = c.i;
    unsigned int r = (x + 0x7fffu + ((x >> 16) & 1u)) >> 16;
    return (unsigned short)r;
}
// order-preserving bf16 -> u16 key (unsigned max == float max)
__device__ __forceinline__ unsigned short bf2key(unsigned short b) {
    return (b & 0x8000u) ? (unsigned short)~b : (unsigned short)(b | 0x8000u);
}
__device__ __forceinline__ unsigned short key2bf(unsigned short k) {
    return (k & 0x8000u) ? (unsigned short)(k ^ 0x8000u) : (unsigned short)~k;
}
__device__ __forceinline__ u16x2 as_u16x2(unsigned int x) {
    union { unsigned int u; u16x2 v; } c; c.u = x; return c.v;
}

// ------------------------------------------------- detect dtypes + zero deg
// flags[0]: edge_index is int64 ; flags[1]: floats are f32
__global__ void detect_zero_kernel(const void* __restrict__ ei, const void* __restrict__ pooled,
                                   int* __restrict__ flags, int* __restrict__ deg) {
    int idx = blockIdx.x * 256 + threadIdx.x;
    deg[idx] = 0;
    if (blockIdx.x == 0 && threadIdx.x < 64) {
        int lane = threadIdx.x;
        const long long* e64 = (const long long*)ei;
        bool ok = true;
        for (int i = lane; i < 512; i += 64) {
            long long v = e64[i];
            if (v < 0 || v >= NODES) ok = false;
        }
        unsigned long long b = __ballot(ok);
        const unsigned short* ph = (const unsigned short*)pooled;
        int hits = 0;
        for (int i = lane; i < 512; i += 64) {
            int e = (ph[i] >> 7) & 0xFF;
            if (e >= 0x90) hits++;   // |v| >= 2^17: impossible for N(0,1) bf16 data
        }
        for (int off = 32; off; off >>= 1) hits += __shfl_down(hits, off);
        if (lane == 0) {
            flags[0] = (b == ~0ull) ? 1 : 0;
            flags[1] = (hits > 8) ? 1 : 0;
        }
    }
}

// ---------------------------------------------------------------- edge sort
__global__ void hist_kernel(const void* __restrict__ ei, int E, const int* __restrict__ flags,
                            int* __restrict__ deg) {
    int e = blockIdx.x * blockDim.x + threadIdx.x;
    if (e >= E) return;
    int d = flags[0] ? (int)((const long long*)ei)[(size_t)E + e]
                     : ((const int*)ei)[(size_t)E + e];
    atomicAdd(&deg[d], 1);
}

__global__ void scan_kernel(const int* __restrict__ deg, int* __restrict__ offs,
                            int* __restrict__ cursor) {
    __shared__ int part[256];
    int tid = threadIdx.x;
    int base = tid * 64;
    int s = 0;
    for (int i = 0; i < 64; ++i) s += deg[base + i];
    part[tid] = s;
    __syncthreads();
    for (int off = 1; off < 256; off <<= 1) {
        int t = (tid >= off) ? part[tid - off] : 0;
        __syncthreads();
        part[tid] += t;
        __syncthreads();
    }
    int run = (tid > 0) ? part[tid - 1] : 0;
    for (int i = 0; i < 64; ++i) {
        int idx = base + i;
        offs[idx] = run;
        cursor[idx] = run;
        run += deg[idx];
    }
    if (tid == 255) offs[NODES] = run;
}

__global__ void scatter_kernel(const void* __restrict__ ei, int E, const int* __restrict__ flags,
                               int* __restrict__ cursor, int* __restrict__ ssrc) {
    int e = blockIdx.x * blockDim.x + threadIdx.x;
    if (e >= E) return;
    int s, d;
    if (flags[0]) {
        const long long* p = (const long long*)ei;
        s = (int)p[e];
        d = (int)p[(size_t)E + e];
    } else {
        const int* p = (const int*)ei;
        s = p[e];
        d = p[(size_t)E + e];
    }
    int pos = atomicAdd(&cursor[d], 1);
    ssrc[pos] = s;
}

// ------------------------------------------- x0 staging + weight prep fused
#define T0 (NODES * K1PAD)
#define S1 (512 * K1PAD)
#define S2 (512 * 256)
__global__ void setup_kernel(const void* __restrict__ pooled, const void* __restrict__ rois,
                             const void* __restrict__ W1, const void* __restrict__ W2,
                             const void* __restrict__ W3, const int* __restrict__ flags,
                             unsigned short* __restrict__ x0p, void* __restrict__ outv,
                             unsigned short* __restrict__ wc1, unsigned short* __restrict__ wc2,
                             unsigned short* __restrict__ wc3) {
    int idx = blockIdx.x * 256 + threadIdx.x;
    bool f32m = flags[1] != 0;
    if (idx < T0) {
        int node = idx / K1PAD;
        int k = idx - node * K1PAD;
        float val = 0.f;
        if (k < 256) {
            val = f32m ? ((const float*)pooled)[(size_t)node * 256 + k]
                       : bf2f(((const unsigned short*)pooled)[(size_t)node * 256 + k]);
        } else if (k < D0) {
            val = f32m ? ((const float*)rois)[(size_t)node * 7 + (k - 256)]
                       : bf2f(((const unsigned short*)rois)[(size_t)node * 7 + (k - 256)]);
        }
        x0p[idx] = f2bf(val);
        if (k < D0) {
            if (f32m) ((float*)outv)[(size_t)node * OUTW + k] = val;
            else      ((unsigned short*)outv)[(size_t)node * OUTW + k] = f2bf(val);
        }
        return;
    }
    idx -= T0;
    if (idx < S1) {
        // layer 1: W1 is [256][526], in=263 padded to 288
        int r = idx / K1PAD;
        int k = idx - r * K1PAD;
        unsigned short val = 0;
        if (k < D0) {
            if (r < 256) {
                float a = f32m ? ((const float*)W1)[(size_t)r * 526 + k]
                               : bf2f(((const unsigned short*)W1)[(size_t)r * 526 + k]);
                val = f2bf(a);
            } else {
                size_t ro = (size_t)(r - 256) * 526;
                float a, b;
                if (f32m) { a = ((const float*)W1)[ro + k]; b = ((const float*)W1)[ro + D0 + k]; }
                else      { a = bf2f(((const unsigned short*)W1)[ro + k]);
                            b = bf2f(((const unsigned short*)W1)[ro + D0 + k]); }
                val = f2bf(b - a);
            }
        }
        wc1[idx] = val;
        return;
    }
    idx -= S1;
    const void* W = (idx < S2) ? W2 : W3;
    unsigned short* wc = (idx < S2) ? wc2 : wc3;
    if (idx >= S2) idx -= S2;
    int r = idx >> 8;
    int k = idx & 255;
    unsigned short val;
    if (r < 256) {
        float a = f32m ? ((const float*)W)[(size_t)r * 512 + k]
                       : bf2f(((const unsigned short*)W)[(size_t)r * 512 + k]);
        val = f2bf(a);
    } else {
        size_t ro = (size_t)(r - 256) * 512;
        float a, b;
        if (f32m) { a = ((const float*)W)[ro + k]; b = ((const float*)W)[ro + 256 + k]; }
        else      { a = bf2f(((const unsigned short*)W)[ro + k]);
                    b = bf2f(((const unsigned short*)W)[ro + 256 + k]); }
        val = f2bf(b - a);
    }
    wc[idx] = val;
}

// ---------------------------------------------------------------- GEMM
// T[M,512] = A[M,K]*Wc[512,K]^T.
// cols 0..255  -> u keys, grouped u32 layout u_g32[g=c>>1][node] (lo=ch 2g, hi=ch 2g+1)
// cols 256..511-> vb_g[g][node][2] = v + bias (f32 pair)
// Dense stores: lanes lr and lr^1 hold adjacent channels for the same rows;
// even lane packs both via shfl_xor(1) and writes uint4 / f32x4.
template <int K>
__global__ __launch_bounds__(256) void gemm_kernel(const unsigned short* __restrict__ A,
                                                   const unsigned short* __restrict__ Wc,
                                                   const void* __restrict__ bias,
                                                   const int* __restrict__ flags,
                                                   unsigned int* __restrict__ u_g32,
                                                   float* __restrict__ vb_g) {
    int lane = threadIdx.x & 63;
    int wave = threadIdx.x >> 6;
    int row0 = blockIdx.x * 64;
    int col0 = blockIdx.y * 256 + wave * 64;
    int lr = lane & 15;
    int kb = (lane >> 4) * 8;
    const unsigned short* Ap = A + (size_t)(row0 + lr) * K + kb;
    const unsigned short* Wp = Wc + (size_t)(col0 + lr) * K + kb;

    f32x4 acc[4][4];
    #pragma unroll
    for (int i = 0; i < 4; ++i)
        #pragma unroll
        for (int j = 0; j < 4; ++j) acc[i][j] = (f32x4){0.f, 0.f, 0.f, 0.f};

    for (int k0 = 0; k0 < K; k0 += 32) {
        bf16x8 a[4], b[4];
        #pragma unroll
        for (int i = 0; i < 4; ++i) a[i] = *reinterpret_cast<const bf16x8*>(Ap + (size_t)i * 16 * K + k0);
        #pragma unroll
        for (int i = 0; i < 4; ++i) b[i] = *reinterpret_cast<const bf16x8*>(Wp + (size_t)i * 16 * K + k0);
        #pragma unroll
        for (int rb = 0; rb < 4; ++rb)
            #pragma unroll
            for (int cb = 0; cb < 4; ++cb)
                acc[rb][cb] = __builtin_amdgcn_mfma_f32_16x16x32_bf16(a[rb], b[cb], acc[rb][cb], 0, 0, 0);
    }

    bool is_u = (blockIdx.y == 0);
    bool f32m = flags[1] != 0;
    bool even = (lane & 1) == 0;
    #pragma unroll
    for (int rb = 0; rb < 4; ++rb) {
        int rbase = row0 + rb * 16 + (lane >> 4) * 4;   // multiple of 4
        #pragma unroll
        for (int cb = 0; cb < 4; ++cb) {
            int c = col0 + cb * 16 + lr;
            if (is_u) {
                unsigned int k[4];
                #pragma unroll
                for (int reg = 0; reg < 4; ++reg) {
                    unsigned int key = bf2key(f2bf(acc[rb][cb][reg]));
                    unsigned int p = (unsigned int)__shfl_xor((int)key, 1);
                    k[reg] = key | (p << 16);
                }
                if (even) {
                    int g = c >> 1;
                    uint4 pk; pk.x = k[0]; pk.y = k[1]; pk.z = k[2]; pk.w = k[3];
                    *(uint4*)(u_g32 + (size_t)g * NODES + rbase) = pk;
                }
            } else {
                int c2 = c - 256;
                float bv = f32m ? ((const float*)bias)[c2]
                                : bf2f(((const unsigned short*)bias)[c2]);
                float s[4], p[4];
                #pragma unroll
                for (int reg = 0; reg < 4; ++reg) {
                    s[reg] = acc[rb][cb][reg] + bv;
                    p[reg] = __shfl_xor(s[reg], 1);
                }
                if (even) {
                    int g = c2 >> 1;
                    float* base = vb_g + (size_t)g * (2 * NODES) + (size_t)rbase * 2;
                    f32x4 v0 = {s[0], p[0], s[1], p[1]};
                    f32x4 v1 = {s[2], p[2], s[3], p[3]};
                    *(f32x4*)base = v0;
                    *(f32x4*)(base + 4) = v1;
                }
            }
        }
    }
}

// ---------------------------------------------------------------- combine
// grid = 4 chunks x 128 groups; block = 1024 threads (16 waves), 64 KB LDS;
// __launch_bounds__(1024,8) caps VGPR<=64 so 2 blocks (32 waves) fit per CU.
// Block stages its group's [16384 x 2ch] key slice into LDS, then
// thread-per-node walks the edge list gathering 4 B/edge from LDS.
__global__ __launch_bounds__(1024, 8) void combine_kernel(const unsigned int* __restrict__ u_g32,
                                                          const float* __restrict__ vb_g,
                                                          const int* __restrict__ offs,
                                                          const int* __restrict__ ssrc,
                                                          unsigned int* __restrict__ xcur_t) {
    __shared__ unsigned int uslice[NODES];   // 64 KB: [node] -> 2 packed keys
    int g = blockIdx.x & (NGRP - 1);
    int chunk = blockIdx.x >> 7;             // 0..3
    int tid = threadIdx.x;

    const uint4* s4 = (const uint4*)(u_g32 + (size_t)g * NODES);
    uint4* d4 = (uint4*)uslice;
    #pragma unroll
    for (int i = 0; i < 4; ++i) d4[tid + i * 1024] = s4[tid + i * 1024];
    __syncthreads();

    const float2* vb2 = (const float2*)(vb_g + (size_t)g * (2 * NODES));
    unsigned int* xt = xcur_t + (size_t)g * NODES;

    #pragma unroll
    for (int k = 0; k < 4; ++k) {
        int n = chunk * 4096 + k * 1024 + tid;
        int s0 = offs[n], s1 = offs[n + 1];
        u16x2 mk = (u16x2)0;
        int e = s0;
        for (; e + 3 < s1; e += 4) {
            int i0 = ssrc[e], i1 = ssrc[e + 1], i2 = ssrc[e + 2], i3 = ssrc[e + 3];
            u16x2 k0 = as_u16x2(uslice[i0]);
            u16x2 k1 = as_u16x2(uslice[i1]);
            u16x2 k2 = as_u16x2(uslice[i2]);
            u16x2 k3 = as_u16x2(uslice[i3]);
            mk = __builtin_elementwise_max(mk, __builtin_elementwise_max(
                     __builtin_elementwise_max(k0, k1), __builtin_elementwise_max(k2, k3)));
        }
        for (; e < s1; ++e)
            mk = __builtin_elementwise_max(mk, as_u16x2(uslice[ssrc[e]]));

        float m0 = bf2f(key2bf(mk[0]));
        float m1 = bf2f(key2bf(mk[1]));
        float2 vv = vb2[n];
        bool nz = (s1 > s0);
        float r0 = nz ? fmaxf(m0 + vv.x, 0.f) : 0.f;
        float r1 = nz ? fmaxf(m1 + vv.y, 0.f) : 0.f;
        xt[n] = (unsigned int)f2bf(r0) | ((unsigned int)f2bf(r1) << 16);
    }
}

// ---------------------------------------------------------------- fixup
// transpose xcur_t[g][node] -> x_cur[node][256] bf16 + out slice (dtype per flag)
__global__ __launch_bounds__(256) void fixup_kernel(const unsigned int* __restrict__ xcur_t,
                                                    const int* __restrict__ flags,
                                                    unsigned short* __restrict__ x_cur,
                                                    void* __restrict__ outv,
                                                    int col_off) {
    __shared__ unsigned int tile[32][NGRP + 1];
    int n0 = blockIdx.x * 32;
    int t = threadIdx.x;
    #pragma unroll
    for (int it = 0; it < 16; ++it) {
        int flat = it * 256 + t;
        int g = flat >> 5, j = flat & 31;
        tile[j][g] = xcur_t[(size_t)g * NODES + n0 + j];
    }
    __syncthreads();
    bool f32m = flags[1] != 0;
    int n = t >> 3, seg = t & 7;
    int node = n0 + n;
    unsigned int* xc = (unsigned int*)(x_cur + (size_t)node * 256) + seg * 16;
    size_t ob = (size_t)node * OUTW + col_off + seg * 32;
    #pragma unroll
    for (int k2 = 0; k2 < 16; ++k2) {
        unsigned int w = tile[n][seg * 16 + k2];
        xc[k2] = w;
        unsigned short h0 = (unsigned short)(w & 0xffff);
        unsigned short h1 = (unsigned short)(w >> 16);
        if (f32m) {
            ((float*)outv)[ob + k2 * 2]     = bf2f(h0);
            ((float*)outv)[ob + k2 * 2 + 1] = bf2f(h1);
        } else {
            ((unsigned short*)outv)[ob + k2 * 2]     = h0;
            ((unsigned short*)outv)[ob + k2 * 2 + 1] = h1;
        }
    }
}

// ---------------------------------------------------------------- launch
extern "C" void kernel_launch(void* const* d_in, const int* in_sizes, int n_in,
                              void* d_out, int out_size, void* d_ws, size_t ws_size,
                              hipStream_t stream) {
    const void* rois   = d_in[0];
    const void* pooled = d_in[1];
    const void* ei     = d_in[2];
    const void* W1 = d_in[3];
    const void* b1 = d_in[4];
    const void* W2 = d_in[5];
    const void* b2 = d_in[6];
    const void* W3 = d_in[7];
    const void* b3 = d_in[8];

    const int E = in_sizes[2] / 2;

    char* ws = (char*)d_ws;
    size_t o = 0;
    auto take = [&](size_t bytes) { size_t cur = o; o += (bytes + 255) & ~(size_t)255; return cur; };
    int* flags           = (int*)(ws + take(8));
    int* deg             = (int*)(ws + take(sizeof(int) * NODES));
    int* offs            = (int*)(ws + take(sizeof(int) * (NODES + 1)));
    int* cursor          = (int*)(ws + take(sizeof(int) * NODES));
    int* ssrc            = (int*)(ws + take(sizeof(int) * (size_t)E));
    unsigned short* x0p  = (unsigned short*)(ws + take(2ull * NODES * K1PAD));
    unsigned short* wc1  = (unsigned short*)(ws + take(2ull * 512 * K1PAD));
    unsigned short* wc2  = (unsigned short*)(ws + take(2ull * 512 * 256));
    unsigned short* wc3  = (unsigned short*)(ws + take(2ull * 512 * 256));
    unsigned int*   u_g  = (unsigned int*)(ws + take(4ull * NODES * NGRP));   // 8 MB
    float*          vb_g = (float*)(ws + take(4ull * NODES * 256));
    unsigned int*  xcurt = (unsigned int*)(ws + take(4ull * NODES * NGRP));   // 8 MB
    unsigned short* xcur = (unsigned short*)(ws + take(2ull * NODES * 256));
    (void)ws_size;

    const int eb = (E + 255) / 256;

    detect_zero_kernel<<<NODES / 256, 256, 0, stream>>>(ei, pooled, flags, deg);
    hist_kernel<<<eb, 256, 0, stream>>>(ei, E, flags, deg);
    scan_kernel<<<1, 256, 0, stream>>>(deg, offs, cursor);
    scatter_kernel<<<eb, 256, 0, stream>>>(ei, E, flags, cursor, ssrc);

    setup_kernel<<<(T0 + S1 + 2 * S2) / 256, 256, 0, stream>>>(pooled, rois, W1, W2, W3, flags,
                                                               x0p, d_out, wc1, wc2, wc3);

    // layer 1
    gemm_kernel<K1PAD><<<dim3(NODES / 64, 2), 256, 0, stream>>>(x0p, wc1, b1, flags, u_g, vb_g);
    combine_kernel<<<4 * NGRP, 1024, 0, stream>>>(u_g, vb_g, offs, ssrc, xcurt);
    fixup_kernel<<<NODES / 32, 256, 0, stream>>>(xcurt, flags, xcur, d_out, D0);

    // layer 2
    gemm_kernel<256><<<dim3(NODES / 64, 2), 256, 0, stream>>>(xcur, wc2, b2, flags, u_g, vb_g);
    combine_kernel<<<4 * NGRP, 1024, 0, stream>>>(u_g, vb_g, offs, ssrc, xcurt);
    fixup_kernel<<<NODES / 32, 256, 0, stream>>>(xcurt, flags, xcur, d_out, D0 + 256);

    // layer 3
    gemm_kernel<256><<<dim3(NODES / 64, 2), 256, 0, stream>>>(xcur, wc3, b3, flags, u_g, vb_g);
    combine_kernel<<<4 * NGRP, 1024, 0, stream>>>(u_g, vb_g, offs, ssrc, xcurt);
    fixup_kernel<<<NODES / 32, 256, 0, stream>>>(xcurt, flags, xcur, d_out, D0 + 512);
}

// Round 11
// 353.697 us; speedup vs baseline: 1.7688x; 1.5145x over previous
//
#include <hip/hip_runtime.h>
#include <stdint.h>

#define NODES 16384
#define D0    263
#define K1PAD 288
#define OUTW  1031   // 263 + 256*3
#define NGRP  128    // channel groups of 2

typedef __attribute__((ext_vector_type(8))) short bf16x8;
typedef __attribute__((ext_vector_type(4))) float f32x4;
typedef __attribute__((ext_vector_type(2))) unsigned short u16x2;
typedef __attribute__((ext_vector_type(4))) unsigned short u16x4;
typedef __attribute__((ext_vector_type(8))) unsigned short u16x8;

__device__ __forceinline__ float bf2f(unsigned short u) {
    union { unsigned int i; float f; } c; c.i = ((unsigned int)u) << 16; return c.f;
}
__device__ __forceinline__ unsigned short f2bf(float f) {
    union { float f; unsigned int i; } c; c.f = f;
    unsigned int x = c.i;
    unsigned int r = (x + 0x7fffu + ((x >> 16) & 1u)) >> 16;
    return (unsigned short)r;
}
// order-preserving bf16 -> u16 key (unsigned max == float max)
__device__ __forceinline__ unsigned short bf2key(unsigned short b) {
    return (b & 0x8000u) ? (unsigned short)~b : (unsigned short)(b | 0x8000u);
}
__device__ __forceinline__ unsigned short key2bf(unsigned short k) {
    return (k & 0x8000u) ? (unsigned short)(k ^ 0x8000u) : (unsigned short)~k;
}
__device__ __forceinline__ u16x2 as_u16x2(unsigned int x) {
    union { unsigned int u; u16x2 v; } c; c.u = x; return c.v;
}

// ------------------------------------------------- detect dtypes + zero deg
__global__ void detect_zero_kernel(const void* __restrict__ ei, const void* __restrict__ pooled,
                                   int* __restrict__ flags, int* __restrict__ deg) {
    int idx = blockIdx.x * 256 + threadIdx.x;
    deg[idx] = 0;
    if (blockIdx.x == 0 && threadIdx.x < 64) {
        int lane = threadIdx.x;
        const long long* e64 = (const long long*)ei;
        bool ok = true;
        for (int i = lane; i < 512; i += 64) {
            long long v = e64[i];
            if (v < 0 || v >= NODES) ok = false;
        }
        unsigned long long b = __ballot(ok);
        const unsigned short* ph = (const unsigned short*)pooled;
        int hits = 0;
        for (int i = lane; i < 512; i += 64) {
            int e = (ph[i] >> 7) & 0xFF;
            if (e >= 0x90) hits++;   // |v| >= 2^17: impossible for N(0,1) bf16 data
        }
        for (int off = 32; off; off >>= 1) hits += __shfl_down(hits, off);
        if (lane == 0) {
            flags[0] = (b == ~0ull) ? 1 : 0;
            flags[1] = (hits > 8) ? 1 : 0;
        }
    }
}

// ---------------------------------------------------------------- edge sort
__global__ void hist_kernel(const void* __restrict__ ei, int E, const int* __restrict__ flags,
                            int* __restrict__ deg) {
    int e = blockIdx.x * blockDim.x + threadIdx.x;
    if (e >= E) return;
    int d = flags[0] ? (int)((const long long*)ei)[(size_t)E + e]
                     : ((const int*)ei)[(size_t)E + e];
    atomicAdd(&deg[d], 1);
}

__global__ void scan_kernel(const int* __restrict__ deg, int* __restrict__ offs,
                            int* __restrict__ cursor) {
    __shared__ int part[256];
    int tid = threadIdx.x;
    int base = tid * 64;
    int s = 0;
    for (int i = 0; i < 64; ++i) s += deg[base + i];
    part[tid] = s;
    __syncthreads();
    for (int off = 1; off < 256; off <<= 1) {
        int t = (tid >= off) ? part[tid - off] : 0;
        __syncthreads();
        part[tid] += t;
        __syncthreads();
    }
    int run = (tid > 0) ? part[tid - 1] : 0;
    for (int i = 0; i < 64; ++i) {
        int idx = base + i;
        offs[idx] = run;
        cursor[idx] = run;
        run += deg[idx];
    }
    if (tid == 255) offs[NODES] = run;
}

__global__ void scatter_kernel(const void* __restrict__ ei, int E, const int* __restrict__ flags,
                               int* __restrict__ cursor, int* __restrict__ ssrc) {
    int e = blockIdx.x * blockDim.x + threadIdx.x;
    if (e >= E) return;
    int s, d;
    if (flags[0]) {
        const long long* p = (const long long*)ei;
        s = (int)p[e];
        d = (int)p[(size_t)E + e];
    } else {
        const int* p = (const int*)ei;
        s = p[e];
        d = p[(size_t)E + e];
    }
    int pos = atomicAdd(&cursor[d], 1);
    ssrc[pos] = s;
}

// ------------------------------------------- padded-transposed edge lists
// nodes in groups of 64 (wave lanes). gmax4[ng] = ceil(max deg in group / 4).
__global__ void gmax_kernel(const int* __restrict__ offs, int* __restrict__ gmax4) {
    int n = blockIdx.x * 256 + threadIdx.x;
    int d = offs[n + 1] - offs[n];
    for (int off = 32; off; off >>= 1) d = max(d, __shfl_down(d, off));
    if ((threadIdx.x & 63) == 0) gmax4[n >> 6] = (d + 3) >> 2;
}

__global__ void gscan_kernel(const int* __restrict__ gmax4, int* __restrict__ gbase4) {
    __shared__ int sh[256];
    int t = threadIdx.x;
    int v = gmax4[t];
    sh[t] = v;
    __syncthreads();
    for (int off = 1; off < 256; off <<= 1) {
        int u = (t >= off) ? sh[t - off] : 0;
        __syncthreads();
        sh[t] += u;
        __syncthreads();
    }
    gbase4[t + 1] = sh[t];
    if (t == 0) gbase4[0] = 0;
}

// et layout: quad-row q of group ng at (gbase4[ng]+q)*256 ints; lane l owns
// ints [l*4 .. l*4+3] = its edges 4q..4q+3 (padded with first edge; max-inv).
__global__ void etfill_kernel(const int* __restrict__ offs, const int* __restrict__ ssrc,
                              const int* __restrict__ gbase4, int* __restrict__ et) {
    int n = blockIdx.x * 256 + threadIdx.x;
    int lane = n & 63, ng = n >> 6;
    int s0 = offs[n];
    int deg = offs[n + 1] - s0;
    int b4 = gbase4[ng];
    int q4 = gbase4[ng + 1] - b4;
    int4* dst = (int4*)et + (size_t)b4 * 64 + lane;
    for (int q = 0; q < q4; ++q) {
        int i0 = q * 4;
        int4 v;
        v.x = deg ? ssrc[s0 + min(i0,     deg - 1)] : 0;
        v.y = deg ? ssrc[s0 + min(i0 + 1, deg - 1)] : 0;
        v.z = deg ? ssrc[s0 + min(i0 + 2, deg - 1)] : 0;
        v.w = deg ? ssrc[s0 + min(i0 + 3, deg - 1)] : 0;
        dst[(size_t)q * 64] = v;
    }
}

// ------------------------------------------- x0 staging + weight prep fused
#define T0 (NODES * K1PAD)
#define S1 (512 * K1PAD)
#define S2 (512 * 256)
__global__ void setup_kernel(const void* __restrict__ pooled, const void* __restrict__ rois,
                             const void* __restrict__ W1, const void* __restrict__ W2,
                             const void* __restrict__ W3, const int* __restrict__ flags,
                             unsigned short* __restrict__ x0p, void* __restrict__ outv,
                             unsigned short* __restrict__ wc1, unsigned short* __restrict__ wc2,
                             unsigned short* __restrict__ wc3) {
    int idx = blockIdx.x * 256 + threadIdx.x;
    bool f32m = flags[1] != 0;
    if (idx < T0) {
        int node = idx / K1PAD;
        int k = idx - node * K1PAD;
        float val = 0.f;
        if (k < 256) {
            val = f32m ? ((const float*)pooled)[(size_t)node * 256 + k]
                       : bf2f(((const unsigned short*)pooled)[(size_t)node * 256 + k]);
        } else if (k < D0) {
            val = f32m ? ((const float*)rois)[(size_t)node * 7 + (k - 256)]
                       : bf2f(((const unsigned short*)rois)[(size_t)node * 7 + (k - 256)]);
        }
        x0p[idx] = f2bf(val);
        if (k < D0) {
            if (f32m) ((float*)outv)[(size_t)node * OUTW + k] = val;
            else      ((unsigned short*)outv)[(size_t)node * OUTW + k] = f2bf(val);
        }
        return;
    }
    idx -= T0;
    if (idx < S1) {
        int r = idx / K1PAD;
        int k = idx - r * K1PAD;
        unsigned short val = 0;
        if (k < D0) {
            if (r < 256) {
                float a = f32m ? ((const float*)W1)[(size_t)r * 526 + k]
                               : bf2f(((const unsigned short*)W1)[(size_t)r * 526 + k]);
                val = f2bf(a);
            } else {
                size_t ro = (size_t)(r - 256) * 526;
                float a, b;
                if (f32m) { a = ((const float*)W1)[ro + k]; b = ((const float*)W1)[ro + D0 + k]; }
                else      { a = bf2f(((const unsigned short*)W1)[ro + k]);
                            b = bf2f(((const unsigned short*)W1)[ro + D0 + k]); }
                val = f2bf(b - a);
            }
        }
        wc1[idx] = val;
        return;
    }
    idx -= S1;
    const void* W = (idx < S2) ? W2 : W3;
    unsigned short* wc = (idx < S2) ? wc2 : wc3;
    if (idx >= S2) idx -= S2;
    int r = idx >> 8;
    int k = idx & 255;
    unsigned short val;
    if (r < 256) {
        float a = f32m ? ((const float*)W)[(size_t)r * 512 + k]
                       : bf2f(((const unsigned short*)W)[(size_t)r * 512 + k]);
        val = f2bf(a);
    } else {
        size_t ro = (size_t)(r - 256) * 512;
        float a, b;
        if (f32m) { a = ((const float*)W)[ro + k]; b = ((const float*)W)[ro + 256 + k]; }
        else      { a = bf2f(((const unsigned short*)W)[ro + k]);
                    b = bf2f(((const unsigned short*)W)[ro + 256 + k]); }
        val = f2bf(b - a);
    }
    wc[idx] = val;
}

// ---------------------------------------------------------------- GEMM
// T[M,512] = A[M,K]*Wc[512,K]^T.
// cols 0..255  -> u keys TRANSPOSED: u_t[c][node]  (one u16x4 store / acc blk)
// cols 256..511-> vb TRANSPOSED:     vb_t[c][node] = v + bias (one f32x4 store)
template <int K>
__global__ __launch_bounds__(256) void gemm_kernel(const unsigned short* __restrict__ A,
                                                   const unsigned short* __restrict__ Wc,
                                                   const void* __restrict__ bias,
                                                   const int* __restrict__ flags,
                                                   unsigned short* __restrict__ u_t,
                                                   float* __restrict__ vb_t) {
    int lane = threadIdx.x & 63;
    int wave = threadIdx.x >> 6;
    int row0 = blockIdx.x * 64;
    int col0 = blockIdx.y * 256 + wave * 64;
    int lr = lane & 15;
    int kb = (lane >> 4) * 8;
    const unsigned short* Ap = A + (size_t)(row0 + lr) * K + kb;
    const unsigned short* Wp = Wc + (size_t)(col0 + lr) * K + kb;

    f32x4 acc[4][4];
    #pragma unroll
    for (int i = 0; i < 4; ++i)
        #pragma unroll
        for (int j = 0; j < 4; ++j) acc[i][j] = (f32x4){0.f, 0.f, 0.f, 0.f};

    for (int k0 = 0; k0 < K; k0 += 32) {
        bf16x8 a[4], b[4];
        #pragma unroll
        for (int i = 0; i < 4; ++i) a[i] = *reinterpret_cast<const bf16x8*>(Ap + (size_t)i * 16 * K + k0);
        #pragma unroll
        for (int i = 0; i < 4; ++i) b[i] = *reinterpret_cast<const bf16x8*>(Wp + (size_t)i * 16 * K + k0);
        #pragma unroll
        for (int rb = 0; rb < 4; ++rb)
            #pragma unroll
            for (int cb = 0; cb < 4; ++cb)
                acc[rb][cb] = __builtin_amdgcn_mfma_f32_16x16x32_bf16(a[rb], b[cb], acc[rb][cb], 0, 0, 0);
    }

    bool is_u = (blockIdx.y == 0);
    bool f32m = flags[1] != 0;
    #pragma unroll
    for (int rb = 0; rb < 4; ++rb) {
        int rbase = row0 + rb * 16 + (lane >> 4) * 4;   // multiple of 4
        #pragma unroll
        for (int cb = 0; cb < 4; ++cb) {
            int c = col0 + cb * 16 + lr;
            if (is_u) {
                u16x4 k4;
                #pragma unroll
                for (int reg = 0; reg < 4; ++reg) k4[reg] = bf2key(f2bf(acc[rb][cb][reg]));
                *(u16x4*)(u_t + (size_t)c * NODES + rbase) = k4;
            } else {
                int c2 = c - 256;
                float bv = f32m ? ((const float*)bias)[c2]
                                : bf2f(((const unsigned short*)bias)[c2]);
                f32x4 w = acc[rb][cb] + bv;
                *(f32x4*)(vb_t + (size_t)c2 * NODES + rbase) = w;
            }
        }
    }
}

// ---------------------------------------------------------------- combine
// grid = 4 chunks x 128 groups; block = 1024 threads, 64 KB LDS, 2 blocks/CU.
// Stage channels (2g, 2g+1) packed into LDS, then wave-per-64-node-group
// walks the PADDED-TRANSPOSED edge lists: one coalesced uint4 load = 4 edges
// per lane, 4 LDS gathers, packed u16 max. Wave-uniform trip count.
__global__ __launch_bounds__(1024, 8) void combine_kernel(const unsigned short* __restrict__ u_t,
                                                          const float* __restrict__ vb_t,
                                                          const int* __restrict__ offs,
                                                          const int* __restrict__ gbase4,
                                                          const int* __restrict__ et,
                                                          unsigned int* __restrict__ xcur_t) {
    __shared__ unsigned int uslice[NODES];   // 64 KB: [node] -> packed (lo=2g, hi=2g+1)
    int g = blockIdx.x & (NGRP - 1);
    int chunk = blockIdx.x >> 7;             // 0..3
    int tid = threadIdx.x;

    const u16x8* lo8 = (const u16x8*)(u_t + (size_t)(2 * g) * NODES);
    const u16x8* hi8 = (const u16x8*)(u_t + (size_t)(2 * g + 1) * NODES);
    #pragma unroll
    for (int i = 0; i < 2; ++i) {
        int p = tid + i * 1024;
        u16x8 lo = lo8[p], hi = hi8[p];
        #pragma unroll
        for (int j = 0; j < 8; ++j)
            uslice[p * 8 + j] = (unsigned int)lo[j] | ((unsigned int)hi[j] << 16);
    }
    __syncthreads();

    unsigned int* xt = xcur_t + (size_t)g * NODES;

    #pragma unroll
    for (int k = 0; k < 4; ++k) {
        int n = chunk * 4096 + k * 1024 + tid;
        int ng = n >> 6;
        int b4 = gbase4[ng];                 // wave-uniform
        int q4 = gbase4[ng + 1] - b4;
        const int4* ep = (const int4*)et + (size_t)b4 * 64 + (tid & 63);

        u16x2 mk = (u16x2)0;
        for (int q = 0; q < q4; ++q) {
            int4 e = ep[(size_t)q * 64];     // coalesced: 4 edges of this lane
            u16x2 k0 = as_u16x2(uslice[e.x]);
            u16x2 k1 = as_u16x2(uslice[e.y]);
            u16x2 k2 = as_u16x2(uslice[e.z]);
            u16x2 k3 = as_u16x2(uslice[e.w]);
            mk = __builtin_elementwise_max(mk, __builtin_elementwise_max(
                     __builtin_elementwise_max(k0, k1), __builtin_elementwise_max(k2, k3)));
        }

        float m0 = bf2f(key2bf(mk[0]));
        float m1 = bf2f(key2bf(mk[1]));
        float v0 = vb_t[(size_t)(2 * g) * NODES + n];
        float v1 = vb_t[(size_t)(2 * g + 1) * NODES + n];
        bool nz = offs[n + 1] > offs[n];
        float r0 = nz ? fmaxf(m0 + v0, 0.f) : 0.f;
        float r1 = nz ? fmaxf(m1 + v1, 0.f) : 0.f;
        xt[n] = (unsigned int)f2bf(r0) | ((unsigned int)f2bf(r1) << 16);
    }
}

// ---------------------------------------------------------------- fixup
// transpose xcur_t[g][node] -> x_cur[node][256] bf16 + out slice (dtype per flag)
__global__ __launch_bounds__(256) void fixup_kernel(const unsigned int* __restrict__ xcur_t,
                                                    const int* __restrict__ flags,
                                                    unsigned short* __restrict__ x_cur,
                                                    void* __restrict__ outv,
                                                    int col_off) {
    __shared__ unsigned int tile[32][NGRP + 1];
    int n0 = blockIdx.x * 32;
    int t = threadIdx.x;
    #pragma unroll
    for (int it = 0; it < 16; ++it) {
        int flat = it * 256 + t;
        int g = flat >> 5, j = flat & 31;
        tile[j][g] = xcur_t[(size_t)g * NODES + n0 + j];
    }
    __syncthreads();
    bool f32m = flags[1] != 0;
    int n = t >> 3, seg = t & 7;
    int node = n0 + n;
    unsigned int* xc = (unsigned int*)(x_cur + (size_t)node * 256) + seg * 16;
    size_t ob = (size_t)node * OUTW + col_off + seg * 32;
    #pragma unroll
    for (int k2 = 0; k2 < 16; ++k2) {
        unsigned int w = tile[n][seg * 16 + k2];
        xc[k2] = w;
        unsigned short h0 = (unsigned short)(w & 0xffff);
        unsigned short h1 = (unsigned short)(w >> 16);
        if (f32m) {
            ((float*)outv)[ob + k2 * 2]     = bf2f(h0);
            ((float*)outv)[ob + k2 * 2 + 1] = bf2f(h1);
        } else {
            ((unsigned short*)outv)[ob + k2 * 2]     = h0;
            ((unsigned short*)outv)[ob + k2 * 2 + 1] = h1;
        }
    }
}

// ---------------------------------------------------------------- launch
extern "C" void kernel_launch(void* const* d_in, const int* in_sizes, int n_in,
                              void* d_out, int out_size, void* d_ws, size_t ws_size,
                              hipStream_t stream) {
    const void* rois   = d_in[0];
    const void* pooled = d_in[1];
    const void* ei     = d_in[2];
    const void* W1 = d_in[3];
    const void* b1 = d_in[4];
    const void* W2 = d_in[5];
    const void* b2 = d_in[6];
    const void* W3 = d_in[7];
    const void* b3 = d_in[8];

    const int E = in_sizes[2] / 2;

    char* ws = (char*)d_ws;
    size_t o = 0;
    auto take = [&](size_t bytes) { size_t cur = o; o += (bytes + 255) & ~(size_t)255; return cur; };
    int* flags           = (int*)(ws + take(8));
    int* deg             = (int*)(ws + take(sizeof(int) * NODES));
    int* offs            = (int*)(ws + take(sizeof(int) * (NODES + 1)));
    int* cursor          = (int*)(ws + take(sizeof(int) * NODES));
    int* ssrc            = (int*)(ws + take(sizeof(int) * (size_t)E));
    int* gmax4           = (int*)(ws + take(sizeof(int) * 256));
    int* gbase4          = (int*)(ws + take(sizeof(int) * 257));
    int* et              = (int*)(ws + take(12ull << 20));   // padded-transposed edges
    unsigned short* x0p  = (unsigned short*)(ws + take(2ull * NODES * K1PAD));
    unsigned short* wc1  = (unsigned short*)(ws + take(2ull * 512 * K1PAD));
    unsigned short* wc2  = (unsigned short*)(ws + take(2ull * 512 * 256));
    unsigned short* wc3  = (unsigned short*)(ws + take(2ull * 512 * 256));
    unsigned short* u_t  = (unsigned short*)(ws + take(2ull * NODES * 256));  // 8 MB
    float*          vb_t = (float*)(ws + take(4ull * NODES * 256));           // 16 MB
    unsigned int*  xcurt = (unsigned int*)(ws + take(4ull * NODES * NGRP));   // 8 MB
    unsigned short* xcur = (unsigned short*)(ws + take(2ull * NODES * 256));
    (void)ws_size;

    const int eb = (E + 255) / 256;

    detect_zero_kernel<<<NODES / 256, 256, 0, stream>>>(ei, pooled, flags, deg);
    hist_kernel<<<eb, 256, 0, stream>>>(ei, E, flags, deg);
    scan_kernel<<<1, 256, 0, stream>>>(deg, offs, cursor);
    scatter_kernel<<<eb, 256, 0, stream>>>(ei, E, flags, cursor, ssrc);
    gmax_kernel<<<NODES / 256, 256, 0, stream>>>(offs, gmax4);
    gscan_kernel<<<1, 256, 0, stream>>>(gmax4, gbase4);
    etfill_kernel<<<NODES / 256, 256, 0, stream>>>(offs, ssrc, gbase4, et);

    setup_kernel<<<(T0 + S1 + 2 * S2) / 256, 256, 0, stream>>>(pooled, rois, W1, W2, W3, flags,
                                                               x0p, d_out, wc1, wc2, wc3);

    // layer 1
    gemm_kernel<K1PAD><<<dim3(NODES / 64, 2), 256, 0, stream>>>(x0p, wc1, b1, flags, u_t, vb_t);
    combine_kernel<<<4 * NGRP, 1024, 0, stream>>>(u_t, vb_t, offs, gbase4, et, xcurt);
    fixup_kernel<<<NODES / 32, 256, 0, stream>>>(xcurt, flags, xcur, d_out, D0);

    // layer 2
    gemm_kernel<256><<<dim3(NODES / 64, 2), 256, 0, stream>>>(xcur, wc2, b2, flags, u_t, vb_t);
    combine_kernel<<<4 * NGRP, 1024, 0, stream>>>(u_t, vb_t, offs, gbase4, et, xcurt);
    fixup_kernel<<<NODES / 32, 256, 0, stream>>>(xcurt, flags, xcur, d_out, D0 + 256);

    // layer 3
    gemm_kernel<256><<<dim3(NODES / 64, 2), 256, 0, stream>>>(xcur, wc3, b3, flags, u_t, vb_t);
    combine_kernel<<<4 * NGRP, 1024, 0, stream>>>(u_t, vb_t, offs, gbase4, et, xcurt);
    fixup_kernel<<<NODES / 32, 256, 0, stream>>>(xcurt, flags, xcur, d_out, D0 + 512);
}

// Round 12
// 323.136 us; speedup vs baseline: 1.9361x; 1.0946x over previous
//
#include <hip/hip_runtime.h>
#include <stdint.h>

#define NODES 16384
#define D0    263
#define K1PAD 288
#define OUTW  1031   // 263 + 256*3

typedef __attribute__((ext_vector_type(8))) short bf16x8;
typedef __attribute__((ext_vector_type(4))) float f32x4;
typedef __attribute__((ext_vector_type(4))) unsigned short u16x4;

__device__ __forceinline__ float bf2f(unsigned short u) {
    union { unsigned int i; float f; } c; c.i = ((unsigned int)u) << 16; return c.f;
}
__device__ __forceinline__ unsigned short f2bf(float f) {
    union { float f; unsigned int i; } c; c.f = f;
    unsigned int x = c.i;
    unsigned int r = (x + 0x7fffu + ((x >> 16) & 1u)) >> 16;
    return (unsigned short)r;
}
// order-preserving bf16 -> u16 key (unsigned max == float max)
__device__ __forceinline__ unsigned short bf2key(unsigned short b) {
    return (b & 0x8000u) ? (unsigned short)~b : (unsigned short)(b | 0x8000u);
}
__device__ __forceinline__ unsigned short key2bf(unsigned short k) {
    return (k & 0x8000u) ? (unsigned short)(k ^ 0x8000u) : (unsigned short)~k;
}
__device__ __forceinline__ u16x4 as_u16x4(uint2 x) {
    union { uint2 u; u16x4 v; } c; c.u = x; return c.v;
}

// ------------------------------------------------- detect dtypes + zero deg
__global__ void detect_zero_kernel(const void* __restrict__ ei, const void* __restrict__ pooled,
                                   int* __restrict__ flags, int* __restrict__ deg) {
    int idx = blockIdx.x * 256 + threadIdx.x;
    deg[idx] = 0;
    if (blockIdx.x == 0 && threadIdx.x < 64) {
        int lane = threadIdx.x;
        const long long* e64 = (const long long*)ei;
        bool ok = true;
        for (int i = lane; i < 512; i += 64) {
            long long v = e64[i];
            if (v < 0 || v >= NODES) ok = false;
        }
        unsigned long long b = __ballot(ok);
        const unsigned short* ph = (const unsigned short*)pooled;
        int hits = 0;
        for (int i = lane; i < 512; i += 64) {
            int e = (ph[i] >> 7) & 0xFF;
            if (e >= 0x90) hits++;   // impossible for N(0,1) bf16 data
        }
        for (int off = 32; off; off >>= 1) hits += __shfl_down(hits, off);
        if (lane == 0) {
            flags[0] = (b == ~0ull) ? 1 : 0;
            flags[1] = (hits > 8) ? 1 : 0;
        }
    }
}

// ---------------------------------------------------------------- edge sort
__global__ void hist_kernel(const void* __restrict__ ei, int E, const int* __restrict__ flags,
                            int* __restrict__ deg) {
    int e = blockIdx.x * blockDim.x + threadIdx.x;
    if (e >= E) return;
    int d = flags[0] ? (int)((const long long*)ei)[(size_t)E + e]
                     : ((const int*)ei)[(size_t)E + e];
    atomicAdd(&deg[d], 1);
}

// scan + group-max quad scan fused (thread t == node-group t of 64 nodes)
__global__ void scan_kernel(const int* __restrict__ deg, int* __restrict__ offs,
                            int* __restrict__ cursor, int* __restrict__ gbase4) {
    __shared__ int part[256], gpart[256];
    int tid = threadIdx.x;
    int base = tid * 64;
    int s = 0, mx = 0;
    for (int i = 0; i < 64; ++i) { int d = deg[base + i]; s += d; mx = max(mx, d); }
    part[tid] = s;
    gpart[tid] = (mx + 3) >> 2;
    __syncthreads();
    for (int off = 1; off < 256; off <<= 1) {
        int t1 = (tid >= off) ? part[tid - off] : 0;
        int t2 = (tid >= off) ? gpart[tid - off] : 0;
        __syncthreads();
        part[tid] += t1; gpart[tid] += t2;
        __syncthreads();
    }
    int run = (tid > 0) ? part[tid - 1] : 0;
    for (int i = 0; i < 64; ++i) {
        int idx = base + i;
        offs[idx] = run;
        cursor[idx] = run;
        run += deg[idx];
    }
    if (tid == 255) offs[NODES] = run;
    gbase4[tid + 1] = gpart[tid];
    if (tid == 0) gbase4[0] = 0;
}

__global__ void scatter_kernel(const void* __restrict__ ei, int E, const int* __restrict__ flags,
                               int* __restrict__ cursor, int* __restrict__ ssrc) {
    int e = blockIdx.x * blockDim.x + threadIdx.x;
    if (e >= E) return;
    int s, d;
    if (flags[0]) {
        const long long* p = (const long long*)ei;
        s = (int)p[e];
        d = (int)p[(size_t)E + e];
    } else {
        const int* p = (const int*)ei;
        s = p[e];
        d = p[(size_t)E + e];
    }
    int pos = atomicAdd(&cursor[d], 1);
    ssrc[pos] = s;
}

// ---------------- setup: x0p staging + weight prep + etfill, one dispatch
#define T0 (NODES * K1PAD)
#define S1 (512 * K1PAD)
#define S2 (512 * 256)
#define SETUP_TOT (T0 + S1 + 2 * S2 + NODES)
__global__ void setup_kernel(const void* __restrict__ pooled, const void* __restrict__ rois,
                             const void* __restrict__ W1, const void* __restrict__ W2,
                             const void* __restrict__ W3, const int* __restrict__ flags,
                             const int* __restrict__ offs, const int* __restrict__ ssrc,
                             const int* __restrict__ gbase4, int* __restrict__ et,
                             unsigned short* __restrict__ x0p,
                             unsigned short* __restrict__ wc1, unsigned short* __restrict__ wc2,
                             unsigned short* __restrict__ wc3) {
    int idx = blockIdx.x * 256 + threadIdx.x;
    bool f32m = flags[1] != 0;
    if (idx < T0) {
        int node = idx / K1PAD;
        int k = idx - node * K1PAD;
        float val = 0.f;
        if (k < 256) {
            val = f32m ? ((const float*)pooled)[(size_t)node * 256 + k]
                       : bf2f(((const unsigned short*)pooled)[(size_t)node * 256 + k]);
        } else if (k < D0) {
            val = f32m ? ((const float*)rois)[(size_t)node * 7 + (k - 256)]
                       : bf2f(((const unsigned short*)rois)[(size_t)node * 7 + (k - 256)]);
        }
        x0p[idx] = f2bf(val);
        return;
    }
    idx -= T0;
    if (idx < S1) {
        int r = idx / K1PAD;
        int k = idx - r * K1PAD;
        unsigned short val = 0;
        if (k < D0) {
            if (r < 256) {
                float a = f32m ? ((const float*)W1)[(size_t)r * 526 + k]
                               : bf2f(((const unsigned short*)W1)[(size_t)r * 526 + k]);
                val = f2bf(a);
            } else {
                size_t ro = (size_t)(r - 256) * 526;
                float a, b;
                if (f32m) { a = ((const float*)W1)[ro + k]; b = ((const float*)W1)[ro + D0 + k]; }
                else      { a = bf2f(((const unsigned short*)W1)[ro + k]);
                            b = bf2f(((const unsigned short*)W1)[ro + D0 + k]); }
                val = f2bf(b - a);
            }
        }
        wc1[idx] = val;
        return;
    }
    idx -= S1;
    if (idx < 2 * S2) {
        const void* W = (idx < S2) ? W2 : W3;
        unsigned short* wc = (idx < S2) ? wc2 : wc3;
        if (idx >= S2) idx -= S2;
        int r = idx >> 8;
        int k = idx & 255;
        unsigned short val;
        if (r < 256) {
            float a = f32m ? ((const float*)W)[(size_t)r * 512 + k]
                           : bf2f(((const unsigned short*)W)[(size_t)r * 512 + k]);
            val = f2bf(a);
        } else {
            size_t ro = (size_t)(r - 256) * 512;
            float a, b;
            if (f32m) { a = ((const float*)W)[ro + k]; b = ((const float*)W)[ro + 256 + k]; }
            else      { a = bf2f(((const unsigned short*)W)[ro + k]);
                        b = bf2f(((const unsigned short*)W)[ro + 256 + k]); }
            val = f2bf(b - a);
        }
        wc[idx] = val;
        return;
    }
    idx -= 2 * S2;
    if (idx < NODES) {
        // etfill: padded-transposed edge lists (pad = first edge, max-invariant)
        int n = idx;
        int lane = n & 63, ng = n >> 6;
        int s0 = offs[n];
        int dg = offs[n + 1] - s0;
        int b4 = gbase4[ng];
        int q4 = gbase4[ng + 1] - b4;
        int4* dst = (int4*)et + (size_t)b4 * 64 + lane;
        for (int q = 0; q < q4; ++q) {
            int i0 = q * 4;
            int4 v;
            v.x = dg ? ssrc[s0 + min(i0,     dg - 1)] : 0;
            v.y = dg ? ssrc[s0 + min(i0 + 1, dg - 1)] : 0;
            v.z = dg ? ssrc[s0 + min(i0 + 2, dg - 1)] : 0;
            v.w = dg ? ssrc[s0 + min(i0 + 3, dg - 1)] : 0;
            dst[(size_t)q * 64] = v;
        }
    }
}

// ---------------------------------------------------------------- GEMM
// T[M,512] = A[M,K]*Wc[512,K]^T.  y==0: cols 0..255 -> u keys; y==1: cols
// 256..511 -> bf16(v+bias).  Both written TRANSPOSED-QUAD via LDS tile:
// out[c4][node][4ch] u16 (c4 = ch>>2), full-line coalesced global stores.
// ALAYOUT 0: A row-major [node][K].  ALAYOUT 1: A transposed-quad [c4][node][4].
template <int K, int ALAYOUT>
__global__ __launch_bounds__(256) void gemm_kernel(const unsigned short* __restrict__ A,
                                                   const unsigned short* __restrict__ Wc,
                                                   const void* __restrict__ bias,
                                                   const int* __restrict__ flags,
                                                   unsigned short* __restrict__ u_t4,
                                                   unsigned short* __restrict__ vb_t4) {
    __shared__ __align__(16) unsigned short tile[64][65][4];   // 33.3 KB
    int lane = threadIdx.x & 63;
    int wave = threadIdx.x >> 6;
    int row0 = blockIdx.x * 64;
    int col0 = blockIdx.y * 256 + wave * 64;
    int lr = lane & 15;
    int kb = (lane >> 4) * 8;
    const unsigned short* Ap = A + (size_t)(row0 + lr) * K + kb;   // ALAYOUT 0
    const unsigned short* Wp = Wc + (size_t)(col0 + lr) * K + kb;

    f32x4 acc[4][4];
    #pragma unroll
    for (int i = 0; i < 4; ++i)
        #pragma unroll
        for (int j = 0; j < 4; ++j) acc[i][j] = (f32x4){0.f, 0.f, 0.f, 0.f};

    for (int k0 = 0; k0 < K; k0 += 32) {
        bf16x8 a[4], b[4];
        if (ALAYOUT == 0) {
            #pragma unroll
            for (int i = 0; i < 4; ++i)
                a[i] = *reinterpret_cast<const bf16x8*>(Ap + (size_t)i * 16 * K + k0);
        } else {
            int c4a = (k0 + kb) >> 2;
            #pragma unroll
            for (int i = 0; i < 4; ++i) {
                int row = row0 + i * 16 + lr;
                uint2 lo = *(const uint2*)(A + ((size_t)c4a * NODES + row) * 4);
                uint2 hi = *(const uint2*)(A + ((size_t)(c4a + 1) * NODES + row) * 4);
                union { uint4 u; bf16x8 v; } pk;
                pk.u.x = lo.x; pk.u.y = lo.y; pk.u.z = hi.x; pk.u.w = hi.y;
                a[i] = pk.v;
            }
        }
        #pragma unroll
        for (int i = 0; i < 4; ++i)
            b[i] = *reinterpret_cast<const bf16x8*>(Wp + (size_t)i * 16 * K + k0);
        #pragma unroll
        for (int rb = 0; rb < 4; ++rb)
            #pragma unroll
            for (int cb = 0; cb < 4; ++cb)
                acc[rb][cb] = __builtin_amdgcn_mfma_f32_16x16x32_bf16(a[rb], b[cb], acc[rb][cb], 0, 0, 0);
    }

    bool is_u = (blockIdx.y == 0);
    bool f32m = flags[1] != 0;
    #pragma unroll
    for (int rb = 0; rb < 4; ++rb) {
        #pragma unroll
        for (int cb = 0; cb < 4; ++cb) {
            int ccol = col0 + cb * 16 + lr;
            int cl = is_u ? ccol : (ccol - 256);
            float bv = 0.f;
            if (!is_u) bv = f32m ? ((const float*)bias)[cl]
                                 : bf2f(((const unsigned short*)bias)[cl]);
            int rloc = rb * 16 + (lane >> 4) * 4;
            #pragma unroll
            for (int reg = 0; reg < 4; ++reg) {
                float v = acc[rb][cb][reg];
                unsigned short val = is_u ? bf2key(f2bf(v)) : f2bf(v + bv);
                tile[cl >> 2][rloc + reg][cl & 3] = val;
            }
        }
    }
    __syncthreads();

    unsigned short* dst = is_u ? u_t4 : vb_t4;
    int c4 = threadIdx.x >> 2, sub = threadIdx.x & 3;
    size_t base = ((size_t)c4 * NODES + row0) * 4;
    #pragma unroll
    for (int i = 0; i < 8; ++i) {
        int n1 = sub * 2 + i * 8;
        uint2 a_ = *(const uint2*)&tile[c4][n1][0];
        uint2 b_ = *(const uint2*)&tile[c4][n1 + 1][0];
        uint4 w; w.x = a_.x; w.y = a_.y; w.z = b_.x; w.w = b_.y;
        *(uint4*)(dst + base + (size_t)n1 * 4) = w;
    }
}

// ---------------------------------------------------------------- combine
// grid = 8 chunks x 64 quad-groups; 1024 threads; 128 KB dynamic LDS holds
// uslice[node] = u16x4 keys of channels 4g..4g+3. Coalesced padded edge walk
// (int4 = 4 edges), ds_read_b64 gathers, packed u16 max. Output bf16 values
// to xq[c4][node] (coalesced); v+bias read from vb_t4 (bf16).
__global__ __launch_bounds__(1024) void combine_kernel(const unsigned short* __restrict__ u_t4,
                                                       const unsigned short* __restrict__ vb_t4,
                                                       const int* __restrict__ offs,
                                                       const int* __restrict__ gbase4,
                                                       const int* __restrict__ et,
                                                       unsigned short* __restrict__ xq) {
    extern __shared__ uint2 uslice[];        // 16384 * 8 B = 128 KB
    int g = blockIdx.x & 63;
    int chunk = blockIdx.x >> 6;             // 0..7
    int tid = threadIdx.x;

    const uint2* src = (const uint2*)(u_t4 + (size_t)g * NODES * 4);
    #pragma unroll
    for (int i = 0; i < 16; ++i) uslice[tid + i * 1024] = src[tid + i * 1024];
    __syncthreads();

    const uint2* vbp = (const uint2*)(vb_t4 + (size_t)g * NODES * 4);
    uint2* xp = (uint2*)(xq + (size_t)g * NODES * 4);

    #pragma unroll
    for (int k = 0; k < 2; ++k) {
        int n = chunk * 2048 + k * 1024 + tid;
        int ng = n >> 6;
        int b4 = gbase4[ng];
        int q4 = gbase4[ng + 1] - b4;
        const int4* ep = (const int4*)et + (size_t)b4 * 64 + (tid & 63);

        u16x4 mk = (u16x4)0;
        for (int q = 0; q < q4; ++q) {
            int4 e = ep[(size_t)q * 64];
            u16x4 k0 = as_u16x4(uslice[e.x]);
            u16x4 k1 = as_u16x4(uslice[e.y]);
            u16x4 k2 = as_u16x4(uslice[e.z]);
            u16x4 k3 = as_u16x4(uslice[e.w]);
            mk = __builtin_elementwise_max(mk, __builtin_elementwise_max(
                     __builtin_elementwise_max(k0, k1), __builtin_elementwise_max(k2, k3)));
        }

        u16x4 vb = as_u16x4(vbp[n]);
        bool nz = offs[n + 1] > offs[n];
        unsigned short h[4];
        #pragma unroll
        for (int j = 0; j < 4; ++j) {
            float r = nz ? fmaxf(bf2f(key2bf(mk[j])) + bf2f(vb[j]), 0.f) : 0.f;
            h[j] = f2bf(r);
        }
        uint2 w;
        w.x = (unsigned int)h[0] | ((unsigned int)h[1] << 16);
        w.y = (unsigned int)h[2] | ((unsigned int)h[3] << 16);
        xp[n] = w;
    }
}

// ---------------------------------------------------------------- assemble
// One kernel writes the entire output: head cols 0..262 from pooled/rois,
// then 3 layer slices from xq1/2/3 via LDS tile transpose. 64 nodes/block.
__global__ __launch_bounds__(256) void assemble_kernel(const void* __restrict__ pooled,
                                                       const void* __restrict__ rois,
                                                       const int* __restrict__ flags,
                                                       const unsigned short* __restrict__ x1,
                                                       const unsigned short* __restrict__ x2,
                                                       const unsigned short* __restrict__ x3,
                                                       void* __restrict__ outv) {
    __shared__ __align__(16) unsigned short tile[64][65][4];
    int n0 = blockIdx.x * 64;
    int t = threadIdx.x;
    bool f32m = flags[1] != 0;

    for (int idx = t; idx < 64 * 263; idx += 256) {
        int n = idx / 263, c = idx - n * 263;
        float val;
        if (c < 256)
            val = f32m ? ((const float*)pooled)[(size_t)(n0 + n) * 256 + c]
                       : bf2f(((const unsigned short*)pooled)[(size_t)(n0 + n) * 256 + c]);
        else
            val = f32m ? ((const float*)rois)[(size_t)(n0 + n) * 7 + (c - 256)]
                       : bf2f(((const unsigned short*)rois)[(size_t)(n0 + n) * 7 + (c - 256)]);
        if (f32m) ((float*)outv)[(size_t)(n0 + n) * OUTW + c] = val;
        else      ((unsigned short*)outv)[(size_t)(n0 + n) * OUTW + c] = f2bf(val);
    }

    const unsigned short* xs[3] = {x1, x2, x3};
    int n = t >> 2, sub = t & 3;
    for (int l = 0; l < 3; ++l) {
        __syncthreads();
        for (int idx = t; idx < 4096; idx += 256) {
            int c4 = idx >> 6, j = idx & 63;
            uint2 w = ((const uint2*)(xs[l]))[(size_t)c4 * NODES + n0 + j];
            *(unsigned int*)&tile[c4][j][0] = w.x;
            *(unsigned int*)&tile[c4][j][2] = w.y;
        }
        __syncthreads();
        size_t ob = (size_t)(n0 + n) * OUTW + D0 + l * 256 + sub * 64;
        for (int c4i = 0; c4i < 16; ++c4i) {
            int c4 = sub * 16 + c4i;
            #pragma unroll
            for (int j = 0; j < 4; ++j) {
                unsigned short h = tile[c4][n][j];
                if (f32m) ((float*)outv)[ob + c4i * 4 + j] = bf2f(h);
                else      ((unsigned short*)outv)[ob + c4i * 4 + j] = h;
            }
        }
    }
}

// ---------------------------------------------------------------- launch
extern "C" void kernel_launch(void* const* d_in, const int* in_sizes, int n_in,
                              void* d_out, int out_size, void* d_ws, size_t ws_size,
                              hipStream_t stream) {
    const void* rois   = d_in[0];
    const void* pooled = d_in[1];
    const void* ei     = d_in[2];
    const void* W1 = d_in[3];
    const void* b1 = d_in[4];
    const void* W2 = d_in[5];
    const void* b2 = d_in[6];
    const void* W3 = d_in[7];
    const void* b3 = d_in[8];

    const int E = in_sizes[2] / 2;

    char* ws = (char*)d_ws;
    size_t o = 0;
    auto take = [&](size_t bytes) { size_t cur = o; o += (bytes + 255) & ~(size_t)255; return cur; };
    int* flags           = (int*)(ws + take(8));
    int* deg             = (int*)(ws + take(sizeof(int) * NODES));
    int* offs            = (int*)(ws + take(sizeof(int) * (NODES + 1)));
    int* cursor          = (int*)(ws + take(sizeof(int) * NODES));
    int* ssrc            = (int*)(ws + take(sizeof(int) * (size_t)E));
    int* gbase4          = (int*)(ws + take(sizeof(int) * 257));
    int* et              = (int*)(ws + take(32ull << 20));
    unsigned short* x0p  = (unsigned short*)(ws + take(2ull * NODES * K1PAD));
    unsigned short* wc1  = (unsigned short*)(ws + take(2ull * 512 * K1PAD));
    unsigned short* wc2  = (unsigned short*)(ws + take(2ull * 512 * 256));
    unsigned short* wc3  = (unsigned short*)(ws + take(2ull * 512 * 256));
    unsigned short* u_t4 = (unsigned short*)(ws + take(2ull * NODES * 256));  // 8 MB keys
    unsigned short* vbt4 = (unsigned short*)(ws + take(2ull * NODES * 256));  // 8 MB bf16
    unsigned short* xq1  = (unsigned short*)(ws + take(2ull * NODES * 256));
    unsigned short* xq2  = (unsigned short*)(ws + take(2ull * NODES * 256));
    unsigned short* xq3  = (unsigned short*)(ws + take(2ull * NODES * 256));
    (void)ws_size;

    const int eb = (E + 255) / 256;

    detect_zero_kernel<<<NODES / 256, 256, 0, stream>>>(ei, pooled, flags, deg);
    hist_kernel<<<eb, 256, 0, stream>>>(ei, E, flags, deg);
    scan_kernel<<<1, 256, 0, stream>>>(deg, offs, cursor, gbase4);
    scatter_kernel<<<eb, 256, 0, stream>>>(ei, E, flags, cursor, ssrc);
    setup_kernel<<<(SETUP_TOT + 255) / 256, 256, 0, stream>>>(pooled, rois, W1, W2, W3, flags,
                                                              offs, ssrc, gbase4, et,
                                                              x0p, wc1, wc2, wc3);

    // layer 1
    gemm_kernel<K1PAD, 0><<<dim3(NODES / 64, 2), 256, 0, stream>>>(x0p, wc1, b1, flags, u_t4, vbt4);
    combine_kernel<<<8 * 64, 1024, 131072, stream>>>(u_t4, vbt4, offs, gbase4, et, xq1);

    // layer 2
    gemm_kernel<256, 1><<<dim3(NODES / 64, 2), 256, 0, stream>>>(xq1, wc2, b2, flags, u_t4, vbt4);
    combine_kernel<<<8 * 64, 1024, 131072, stream>>>(u_t4, vbt4, offs, gbase4, et, xq2);

    // layer 3
    gemm_kernel<256, 1><<<dim3(NODES / 64, 2), 256, 0, stream>>>(xq2, wc3, b3, flags, u_t4, vbt4);
    combine_kernel<<<8 * 64, 1024, 131072, stream>>>(u_t4, vbt4, offs, gbase4, et, xq3);

    assemble_kernel<<<NODES / 64, 256, 0, stream>>>(pooled, rois, flags, xq1, xq2, xq3, d_out);
}